// Round 1
// 6613.863 us; speedup vs baseline: 1.1204x; 1.1204x over previous
//
#include <hip/hip_runtime.h>
#include <hip/hip_bf16.h>

typedef __attribute__((ext_vector_type(8))) short bf16x8;   // 8 bf16 MFMA A/B frag
typedef __attribute__((ext_vector_type(4))) short bf16x4;   // 4 bf16 (8B)
typedef __attribute__((ext_vector_type(4))) float floatx4;  // MFMA C/D frag / 16B container

#define MFMA_BF16_16x16x32(a, b, c) __builtin_amdgcn_mfma_f32_16x16x32_bf16((a), (b), (c), 0, 0, 0)

#define B_SZ 64
#define T_SZ 512
#define DIN  1024
#define DH   2048
#define DOUT 1024
#define NBLK 64          // persistent grid
#define NTHR 512         // 8 waves/block -> 2 waves/SIMD
#define NW   8
#define KW   (DH / NW)   // 256 K-range per wave
#define COLS 32          // h columns owned per block
#define HELEMS ((size_t)B_SZ * DH)   // bf16 elems per h buffer (m-major [64][2048])

union f4b8 { floatx4 f; bf16x8 b; };
__device__ inline bf16x8 asb(floatx4 f) { f4b8 u; u.f = f; return u.b; }

__device__ inline unsigned ld_coh(const unsigned* p) {
  return __hip_atomic_load(p, __ATOMIC_RELAXED, __HIP_MEMORY_SCOPE_AGENT);
}
__device__ inline void st_coh(unsigned* p, unsigned v) {
  __hip_atomic_store(p, v, __ATOMIC_RELAXED, __HIP_MEMORY_SCOPE_AGENT);
}

__device__ inline bf16x8 cvt8(float4 a, float4 b) {
  union { bf16x8 v; __hip_bfloat16 h[8]; } u;
  u.h[0] = __float2bfloat16(a.x); u.h[1] = __float2bfloat16(a.y);
  u.h[2] = __float2bfloat16(a.z); u.h[3] = __float2bfloat16(a.w);
  u.h[4] = __float2bfloat16(b.x); u.h[5] = __float2bfloat16(b.y);
  u.h[6] = __float2bfloat16(b.z); u.h[7] = __float2bfloat16(b.w);
  return u.v;
}

// ---------------------------------------------------------------------------
// fp32 -> bf16 quantize (RNE), 8 elems/thread.
// ---------------------------------------------------------------------------
__global__ __launch_bounds__(256) void f32_to_bf16(
    const float* __restrict__ in, __hip_bfloat16* __restrict__ out, long n)
{
  long i = ((long)blockIdx.x * 256 + threadIdx.x) * 8;
  if (i + 8 <= n) {
    float4 a = *(const float4*)(in + i);
    float4 b = *(const float4*)(in + i + 4);
    *(bf16x8*)(out + i) = cvt8(a, b);
  }
}

// ---------------------------------------------------------------------------
// Kernel 1: XH = X @ Wxh^T + bxh  (fp32 in, bf16 out). 128x128 tile, BK=64.
// (unchanged, known-good)
// ---------------------------------------------------------------------------
__global__ __launch_bounds__(256) void xh_gemm(
    const float* __restrict__ X,
    const float* __restrict__ W,
    const float* __restrict__ bias,
    __hip_bfloat16* __restrict__ XH)
{
  const int K = DIN;
  const int N = DH;
  __shared__ __hip_bfloat16 As[128][64];
  __shared__ __hip_bfloat16 Bs[128][64];

  const int nb  = N / 128;
  const int bm  = blockIdx.x / nb;
  const int bn  = blockIdx.x % nb;
  const int m0  = bm * 128, n0 = bn * 128;
  const int tid = threadIdx.x;
  const int lane = tid & 63;
  const int wave = tid >> 6;
  const int wm  = (wave >> 1) * 64;
  const int wn  = (wave & 1) * 64;
  const int col = lane & 15;
  const int quad = lane >> 4;

  const floatx4 Z = {0.f, 0.f, 0.f, 0.f};
  floatx4 acc[4][4];
  #pragma unroll
  for (int i = 0; i < 4; ++i)
    #pragma unroll
    for (int j = 0; j < 4; ++j) acc[i][j] = Z;

  const int srow = tid >> 3;
  const int scol = (tid & 7) * 8;

  for (int k0 = 0; k0 < K; k0 += 64) {
    __syncthreads();
    #pragma unroll
    for (int p = 0; p < 4; ++p) {
      int r = srow + p * 32;
      const float* xs = &X[(long)(m0 + r) * K + k0 + scol];
      const float* wsrc = &W[(long)(n0 + r) * K + k0 + scol];
      *(bf16x8*)(&As[r][scol]) = cvt8(*(const float4*)xs,   *(const float4*)(xs + 4));
      *(bf16x8*)(&Bs[r][scol]) = cvt8(*(const float4*)wsrc, *(const float4*)(wsrc + 4));
    }
    __syncthreads();
    #pragma unroll
    for (int kk = 0; kk < 64; kk += 32) {
      const int kr = kk + quad * 8;
      bf16x8 a[4], b[4];
      #pragma unroll
      for (int i = 0; i < 4; ++i) a[i] = *(const bf16x8*)(&As[wm + i*16 + col][kr]);
      #pragma unroll
      for (int j = 0; j < 4; ++j) b[j] = *(const bf16x8*)(&Bs[wn + j*16 + col][kr]);
      #pragma unroll
      for (int i = 0; i < 4; ++i)
        #pragma unroll
        for (int j = 0; j < 4; ++j)
          acc[i][j] = MFMA_BF16_16x16x32(a[i], b[j], acc[i][j]);
    }
  }

  #pragma unroll
  for (int j = 0; j < 4; ++j) {
    const int n = n0 + wn + j*16 + col;
    const float bv = bias[n];
    #pragma unroll
    for (int i = 0; i < 4; ++i) {
      const int mr = m0 + wm + i*16 + quad*4;
      #pragma unroll
      for (int r = 0; r < 4; ++r)
        XH[(long)(mr + r) * N + n] = __float2bfloat16(acc[i][j][r] + bv);
    }
  }
}

// ---------------------------------------------------------------------------
// Grid barrier with fence-based coherence:
//   release fence (buffer_wbl2: flush this XCD's dirty h lines to MALL)
//   -> slot store -> poll all 64 slots -> acquire fence (buffer_inv: drop
//   stale L1/L2 lines). h itself is then accessed with PLAIN cached loads /
//   stores: full-width b128, compiler-scheduled, and L2-shared between the
//   8 blocks of an XCD (they all read the same 256 KiB of h).
// ---------------------------------------------------------------------------
__device__ inline void arrive_and_wait(unsigned* slots, unsigned want, int bid) {
  __syncthreads();                       // all waves' h stores drained to L2 (vmcnt0)
  const int tid = threadIdx.x;
  if (tid == 0) {
    __builtin_amdgcn_fence(__ATOMIC_RELEASE, "agent");   // buffer_wbl2: L2 -> MALL
    st_coh(slots + (size_t)bid * 64, want);
  }
  if (tid < 64) {
    while (ld_coh(slots + (size_t)tid * 64) < want)
      __builtin_amdgcn_s_sleep(1);
    __builtin_amdgcn_fence(__ATOMIC_ACQUIRE, "agent");   // buffer_inv: drop stale L1/L2
  }
  __syncthreads();
}

// ---------------------------------------------------------------------------
// Kernel 2: persistent Elman recurrence + final projection.
//   64 blocks x 512 thr (8 waves). Wave w owns K-slice [w*256, w*256+256),
//   block owns 32 h-columns; Whh slice pinned in regs (64 VGPR/thread,
//   grid total = full 8 MiB). h in plain m-major bf16 [2][64][2048]:
//   A-frag = ONE b128 load (vs 4 scalar coherent dwords before).
// ---------------------------------------------------------------------------
__global__ __launch_bounds__(NTHR, 2) void elman_persistent(
    const __hip_bfloat16* __restrict__ XH,    // [64][512][2048] bf16
    const __hip_bfloat16* __restrict__ Whh,   // [2048][2048] bf16
    const __hip_bfloat16* __restrict__ Why,   // [1024][2048] bf16
    const float* __restrict__ bhy,            // [1024] fp32
    __hip_bfloat16* __restrict__ hbuf,        // [2][64][2048] bf16, m-major
    float* __restrict__ Y,                    // [64][1024] fp32 = d_out
    unsigned* __restrict__ slots)             // 64 x 256B
{
  __shared__ __align__(16) float partial[NW][B_SZ][COLS + 4];  // [8][64][36]
  const int tid  = threadIdx.x;
  const int lane = tid & 63;
  const int wave = tid >> 6;        // 0..7
  const int bid  = blockIdx.x;
  const int n0   = bid * COLS;
  const int col  = lane & 15;
  const int quad = lane >> 4;
  const int kw   = wave * KW;       // this wave's K base

  const int mrow = tid >> 3;        // reduce/store: batch row (0..63)
  const int g    = tid & 3 | (tid & 7);  // (kept simple below)
  const int grp  = tid & 7;         // 8 col-groups of 4
  const int mcol = grp * 4;

  // Pin Whh B-frags (asm anti-remat). 2 n-frags x 8 k16 x 16B = 64 VGPR.
  floatx4 wreg[2][8];
  #pragma unroll
  for (int nf = 0; nf < 2; ++nf) {
    const __hip_bfloat16* wrow = Whh + (long)(n0 + nf*16 + col) * DH + kw + quad * 8;
    #pragma unroll
    for (int k16 = 0; k16 < 8; ++k16) {
      wreg[nf][k16] = *(const floatx4*)(wrow + k16 * 32);
      asm volatile("" : "+v"(wreg[nf][k16]));
    }
  }

  // h0 = 0 for our slice (buffer 0): 8B/thread, coalesced
  *(unsigned long long*)(hbuf + (size_t)mrow * DH + n0 + mcol) = 0ull;
  arrive_and_wait(slots, 1u, bid);

  // XH stream: this thread's 8B chunk per t; prefetched one step ahead.
  const __hip_bfloat16* xptr = XH + (size_t)mrow * T_SZ * DH + n0 + mcol;
  bf16x4 xv = *(const bf16x4*)xptr;   // t = 0

  int cur = 0;
  const floatx4 Z = {0.f, 0.f, 0.f, 0.f};

  for (int t = 0; t < T_SZ; ++t) {
    bf16x4 xv_next = xv;
    if (t + 1 < T_SZ) xv_next = *(const bf16x4*)(xptr + (size_t)(t + 1) * DH);

    const __hip_bfloat16* hc = hbuf + (size_t)cur * HELEMS;
    floatx4 acc[4][2];
    #pragma unroll
    for (int i = 0; i < 4; ++i) { acc[i][0] = Z; acc[i][1] = Z; }

    #pragma unroll
    for (int k16 = 0; k16 < 8; ++k16) {
      const __hip_bfloat16* pk = hc + kw + k16 * 32 + quad * 8;
      bf16x8 a[4];
      #pragma unroll
      for (int i = 0; i < 4; ++i)
        a[i] = *(const bf16x8*)(pk + (size_t)(i*16 + col) * DH);
      #pragma unroll
      for (int i = 0; i < 4; ++i) {
        acc[i][0] = MFMA_BF16_16x16x32(a[i], asb(wreg[0][k16]), acc[i][0]);
        acc[i][1] = MFMA_BF16_16x16x32(a[i], asb(wreg[1][k16]), acc[i][1]);
      }
    }
    // partials to LDS (C/D: m = i*16+quad*4+r, n = nf*16+col)
    #pragma unroll
    for (int i = 0; i < 4; ++i)
      #pragma unroll
      for (int nf = 0; nf < 2; ++nf)
        #pragma unroll
        for (int r = 0; r < 4; ++r)
          partial[wave][i*16 + quad*4 + r][nf*16 + col] = acc[i][nf][r];
    __syncthreads();
    // reduce 8 waves (b128 reads), + xh_t, relu, pack 4 n-cols, plain store
    {
      floatx4 s = Z;
      #pragma unroll
      for (int w = 0; w < NW; ++w)
        s += *(const floatx4*)(&partial[w][mrow][mcol]);
      union { bf16x4 v; __hip_bfloat16 hh[4]; unsigned long long q; } o, xu;
      xu.v = xv;
      #pragma unroll
      for (int c = 0; c < 4; ++c) {
        float v = s[c] + __bfloat162float(xu.hh[c]);
        v = v > 0.f ? v : 0.f;
        o.hh[c] = __float2bfloat16(v);
      }
      *(unsigned long long*)(hbuf + (size_t)(1 - cur) * HELEMS
                             + (size_t)mrow * DH + n0 + mcol) = o.q;
    }
    arrive_and_wait(slots, (unsigned)(t + 2), bid);
    cur ^= 1;
    xv = xv_next;
  }

  // Final projection: y = h_final @ Why^T + bhy  (blocks 0..31, fp32 out)
  if (n0 < DOUT) {
    const __hip_bfloat16* hc = hbuf + (size_t)cur * HELEMS;
    floatx4 acc[4][2];
    #pragma unroll
    for (int i = 0; i < 4; ++i) { acc[i][0] = Z; acc[i][1] = Z; }
    #pragma unroll
    for (int k16 = 0; k16 < 8; ++k16) {
      bf16x8 b0 = *(const bf16x8*)(Why + (long)(n0 +      col) * DH + kw + k16*32 + quad*8);
      bf16x8 b1 = *(const bf16x8*)(Why + (long)(n0 + 16 + col) * DH + kw + k16*32 + quad*8);
      const __hip_bfloat16* pk = hc + kw + k16 * 32 + quad * 8;
      #pragma unroll
      for (int i = 0; i < 4; ++i) {
        bf16x8 a = *(const bf16x8*)(pk + (size_t)(i*16 + col) * DH);
        acc[i][0] = MFMA_BF16_16x16x32(a, b0, acc[i][0]);
        acc[i][1] = MFMA_BF16_16x16x32(a, b1, acc[i][1]);
      }
    }
    #pragma unroll
    for (int i = 0; i < 4; ++i)
      #pragma unroll
      for (int nf = 0; nf < 2; ++nf)
        #pragma unroll
        for (int r = 0; r < 4; ++r)
          partial[wave][i*16 + quad*4 + r][nf*16 + col] = acc[i][nf][r];
    __syncthreads();
    {
      floatx4 s = Z;
      #pragma unroll
      for (int w = 0; w < NW; ++w)
        s += *(const floatx4*)(&partial[w][mrow][mcol]);
      float4 bv = *(const float4*)(&bhy[n0 + mcol]);
      float4 out;
      out.x = s[0] + bv.x; out.y = s[1] + bv.y;
      out.z = s[2] + bv.z; out.w = s[3] + bv.w;
      *(float4*)(&Y[(size_t)mrow * DOUT + n0 + mcol]) = out;
    }
  }
}

// ---------------------------------------------------------------------------
extern "C" void kernel_launch(void* const* d_in, const int* in_sizes, int n_in,
                              void* d_out, int out_size, void* d_ws, size_t ws_size,
                              hipStream_t stream) {
  const float* x   = (const float*)d_in[0];
  const float* Wxh = (const float*)d_in[1];
  const float* bxh = (const float*)d_in[2];
  const float* Whh = (const float*)d_in[3];
  const float* Why = (const float*)d_in[4];
  const float* bhy = (const float*)d_in[5];
  float* y = (float*)d_out;

  char* ws = (char*)d_ws;
  const size_t XH_BYTES  = (size_t)B_SZ * T_SZ * DH * 2;   // 128 MiB
  const size_t WHH_BYTES = (size_t)DH * DH * 2;            // 8 MiB
  const size_t WHY_BYTES = (size_t)DOUT * DH * 2;          // 4 MiB
  const size_t H_BYTES   = (size_t)2 * HELEMS * 2;         // 512 KiB
  const size_t BAR_BYTES = 64 * 256;                       // 64 slots
  __hip_bfloat16* XH     = (__hip_bfloat16*)ws;
  __hip_bfloat16* Whh_bf = (__hip_bfloat16*)(ws + XH_BYTES);
  __hip_bfloat16* Why_bf = (__hip_bfloat16*)(ws + XH_BYTES + WHH_BYTES);
  __hip_bfloat16* hbuf   = (__hip_bfloat16*)(ws + XH_BYTES + WHH_BYTES + WHY_BYTES);
  unsigned* slots        = (unsigned*)(ws + XH_BYTES + WHH_BYTES + WHY_BYTES + H_BYTES);

  hipMemsetAsync(slots, 0, BAR_BYTES, stream);
  f32_to_bf16<<<dim3((DH*DH)/(256*8)),   dim3(256), 0, stream>>>(Whh, Whh_bf, (long)DH*DH);
  f32_to_bf16<<<dim3((DOUT*DH)/(256*8)), dim3(256), 0, stream>>>(Why, Why_bf, (long)DOUT*DH);
  xh_gemm<<<dim3((32768/128) * (DH/128)), dim3(256), 0, stream>>>(x, Wxh, bxh, XH);
  elman_persistent<<<dim3(NBLK), dim3(NTHR), 0, stream>>>(
      XH, Whh_bf, Why_bf, bhy, hbuf, y, slots);
}

// Round 2
// 5484.874 us; speedup vs baseline: 1.3510x; 1.2058x over previous
//
#include <hip/hip_runtime.h>
#include <hip/hip_bf16.h>

typedef __attribute__((ext_vector_type(8))) short bf16x8;   // 8 bf16 MFMA A/B frag
typedef __attribute__((ext_vector_type(4))) short bf16x4;   // 4 bf16 (8B)
typedef __attribute__((ext_vector_type(4))) float floatx4;  // MFMA C/D frag / 16B container

#define MFMA_BF16_16x16x32(a, b, c) __builtin_amdgcn_mfma_f32_16x16x32_bf16((a), (b), (c), 0, 0, 0)

#define B_SZ 64
#define T_SZ 512
#define DIN  1024
#define DH   2048
#define DOUT 1024
#define NBLK 64          // persistent grid
#define NTHR 512         // 8 waves/block -> 2 waves/SIMD
#define NW   8
#define KW   (DH / NW)   // 256 K-range per wave
#define COLS 32          // h columns owned per block
#define HELEMS ((size_t)B_SZ * DH)   // bf16 elems per h buffer (m-major [64][2048])

union f4b8 { floatx4 f; bf16x8 b; };
__device__ inline bf16x8 asb(floatx4 f) { f4b8 u; u.f = f; return u.b; }

__device__ inline unsigned ld_coh(const unsigned* p) {
  return __hip_atomic_load(p, __ATOMIC_RELAXED, __HIP_MEMORY_SCOPE_AGENT);
}
__device__ inline void st_coh(unsigned* p, unsigned v) {
  __hip_atomic_store(p, v, __ATOMIC_RELAXED, __HIP_MEMORY_SCOPE_AGENT);
}
__device__ inline void st_coh64(unsigned long long* p, unsigned long long v) {
  __hip_atomic_store(p, v, __ATOMIC_RELAXED, __HIP_MEMORY_SCOPE_AGENT);
}

// MALL-direct coherent loads (bypass L1+L2): no cache-wide fences needed.
#define LD128_COH(dst, ptr) \
  asm volatile("global_load_dwordx4 %0, %1, off sc0 sc1" : "=v"(dst) : "v"(ptr))
#define LD64_COH(dst, ptr) \
  asm volatile("global_load_dwordx2 %0, %1, off sc0 sc1" : "=v"(dst) : "v"(ptr))
// Counted wait + scheduler fence (rule #18: keep MFMAs below the waitcnt).
#define WAIT_VM(n) do { \
  asm volatile("s_waitcnt vmcnt(" n ")" ::: "memory"); \
  __builtin_amdgcn_sched_barrier(0); } while (0)

// Issue the 8 A-frag loads for k16 = 2g, 2g+1 (i = 0..3 rows x 2 k-halves).
#define ISSUE_GROUP(Ab, g) do { \
  const __hip_bfloat16* _p0 = hrow + (size_t)(2*(g)) * 32; \
  const __hip_bfloat16* _p1 = hrow + (size_t)(2*(g)+1) * 32; \
  LD128_COH(Ab[0], _p0); \
  LD128_COH(Ab[1], _p0 + (size_t)16*DH); \
  LD128_COH(Ab[2], _p0 + (size_t)32*DH); \
  LD128_COH(Ab[3], _p0 + (size_t)48*DH); \
  LD128_COH(Ab[4], _p1); \
  LD128_COH(Ab[5], _p1 + (size_t)16*DH); \
  LD128_COH(Ab[6], _p1 + (size_t)32*DH); \
  LD128_COH(Ab[7], _p1 + (size_t)48*DH); \
} while (0)

// 16 MFMAs consuming group g (k16 = 2g, 2g+1).
#define MFMA_GROUP(Ab, g) do { \
  _Pragma("unroll") \
  for (int _i = 0; _i < 4; ++_i) { \
    acc[_i][0] = MFMA_BF16_16x16x32(Ab[_i], asb(wreg[0][2*(g)]), acc[_i][0]); \
    acc[_i][1] = MFMA_BF16_16x16x32(Ab[_i], asb(wreg[1][2*(g)]), acc[_i][1]); \
  } \
  _Pragma("unroll") \
  for (int _i = 0; _i < 4; ++_i) { \
    acc[_i][0] = MFMA_BF16_16x16x32(Ab[4+_i], asb(wreg[0][2*(g)+1]), acc[_i][0]); \
    acc[_i][1] = MFMA_BF16_16x16x32(Ab[4+_i], asb(wreg[1][2*(g)+1]), acc[_i][1]); \
  } \
} while (0)

__device__ inline bf16x8 cvt8(float4 a, float4 b) {
  union { bf16x8 v; __hip_bfloat16 h[8]; } u;
  u.h[0] = __float2bfloat16(a.x); u.h[1] = __float2bfloat16(a.y);
  u.h[2] = __float2bfloat16(a.z); u.h[3] = __float2bfloat16(a.w);
  u.h[4] = __float2bfloat16(b.x); u.h[5] = __float2bfloat16(b.y);
  u.h[6] = __float2bfloat16(b.z); u.h[7] = __float2bfloat16(b.w);
  return u.v;
}

// ---------------------------------------------------------------------------
// fp32 -> bf16 quantize (RNE), 8 elems/thread.
// ---------------------------------------------------------------------------
__global__ __launch_bounds__(256) void f32_to_bf16(
    const float* __restrict__ in, __hip_bfloat16* __restrict__ out, long n)
{
  long i = ((long)blockIdx.x * 256 + threadIdx.x) * 8;
  if (i + 8 <= n) {
    float4 a = *(const float4*)(in + i);
    float4 b = *(const float4*)(in + i + 4);
    *(bf16x8*)(out + i) = cvt8(a, b);
  }
}

// ---------------------------------------------------------------------------
// Kernel 1: XH = X @ Wxh^T + bxh  (fp32 in, bf16 out). 128x128 tile, BK=64.
// (unchanged, known-good)
// ---------------------------------------------------------------------------
__global__ __launch_bounds__(256) void xh_gemm(
    const float* __restrict__ X,
    const float* __restrict__ W,
    const float* __restrict__ bias,
    __hip_bfloat16* __restrict__ XH)
{
  const int K = DIN;
  const int N = DH;
  __shared__ __hip_bfloat16 As[128][64];
  __shared__ __hip_bfloat16 Bs[128][64];

  const int nb  = N / 128;
  const int bm  = blockIdx.x / nb;
  const int bn  = blockIdx.x % nb;
  const int m0  = bm * 128, n0 = bn * 128;
  const int tid = threadIdx.x;
  const int lane = tid & 63;
  const int wave = tid >> 6;
  const int wm  = (wave >> 1) * 64;
  const int wn  = (wave & 1) * 64;
  const int col = lane & 15;
  const int quad = lane >> 4;

  const floatx4 Z = {0.f, 0.f, 0.f, 0.f};
  floatx4 acc[4][4];
  #pragma unroll
  for (int i = 0; i < 4; ++i)
    #pragma unroll
    for (int j = 0; j < 4; ++j) acc[i][j] = Z;

  const int srow = tid >> 3;
  const int scol = (tid & 7) * 8;

  for (int k0 = 0; k0 < K; k0 += 64) {
    __syncthreads();
    #pragma unroll
    for (int p = 0; p < 4; ++p) {
      int r = srow + p * 32;
      const float* xs = &X[(long)(m0 + r) * K + k0 + scol];
      const float* wsrc = &W[(long)(n0 + r) * K + k0 + scol];
      *(bf16x8*)(&As[r][scol]) = cvt8(*(const float4*)xs,   *(const float4*)(xs + 4));
      *(bf16x8*)(&Bs[r][scol]) = cvt8(*(const float4*)wsrc, *(const float4*)(wsrc + 4));
    }
    __syncthreads();
    #pragma unroll
    for (int kk = 0; kk < 64; kk += 32) {
      const int kr = kk + quad * 8;
      bf16x8 a[4], b[4];
      #pragma unroll
      for (int i = 0; i < 4; ++i) a[i] = *(const bf16x8*)(&As[wm + i*16 + col][kr]);
      #pragma unroll
      for (int j = 0; j < 4; ++j) b[j] = *(const bf16x8*)(&Bs[wn + j*16 + col][kr]);
      #pragma unroll
      for (int i = 0; i < 4; ++i)
        #pragma unroll
        for (int j = 0; j < 4; ++j)
          acc[i][j] = MFMA_BF16_16x16x32(a[i], b[j], acc[i][j]);
    }
  }

  #pragma unroll
  for (int j = 0; j < 4; ++j) {
    const int n = n0 + wn + j*16 + col;
    const float bv = bias[n];
    #pragma unroll
    for (int i = 0; i < 4; ++i) {
      const int mr = m0 + wm + i*16 + quad*4;
      #pragma unroll
      for (int r = 0; r < 4; ++r)
        XH[(long)(mr + r) * N + n] = __float2bfloat16(acc[i][j][r] + bv);
    }
  }
}

// ---------------------------------------------------------------------------
// Flat-slot grid barrier (R0 form, no cache fences): all h traffic is
// MALL-direct (sc0 sc1), so the only ordering needed is vmcnt(0) drain of
// this wave's write-through stores before the slot store.
// ---------------------------------------------------------------------------
__device__ inline void arrive_and_wait(unsigned* slots, unsigned want, int bid) {
  asm volatile("s_waitcnt vmcnt(0)" ::: "memory");
  __syncthreads();
  const int tid = threadIdx.x;
  if (tid == 0)
    st_coh(slots + (size_t)bid * 64, want);
  if (tid < 64) {
    while (ld_coh(slots + (size_t)tid * 64) < want)
      __builtin_amdgcn_s_sleep(1);
  }
  __syncthreads();
}

// ---------------------------------------------------------------------------
// Kernel 2: persistent Elman recurrence + final projection.
//   64 blocks x 512 thr (8 waves). Wave w owns K-slice [w*256, w*256+256),
//   block owns 32 h-columns; Whh slice pinned in regs. h exchanged via
//   MALL-direct b128 loads with counted vmcnt pipelining (issue-all-early,
//   one exposed round trip per step) and write-through u64 atomic stores.
// ---------------------------------------------------------------------------
__global__ __launch_bounds__(NTHR, 2) void elman_persistent(
    const __hip_bfloat16* __restrict__ XH,    // [64][512][2048] bf16
    const __hip_bfloat16* __restrict__ Whh,   // [2048][2048] bf16
    const __hip_bfloat16* __restrict__ Why,   // [1024][2048] bf16
    const float* __restrict__ bhy,            // [1024] fp32
    __hip_bfloat16* __restrict__ hbuf,        // [2][64][2048] bf16, m-major
    float* __restrict__ Y,                    // [64][1024] fp32 = d_out
    unsigned* __restrict__ slots)             // 64 x 256B
{
  __shared__ __align__(16) float partial[NW][B_SZ][COLS + 4];  // [8][64][36]
  const int tid  = threadIdx.x;
  const int lane = tid & 63;
  const int wave = tid >> 6;        // 0..7
  const int bid  = blockIdx.x;
  const int n0   = bid * COLS;
  const int col  = lane & 15;
  const int quad = lane >> 4;
  const int kw   = wave * KW;       // this wave's K base

  const int mrow = tid >> 3;        // reduce/store: batch row (0..63)
  const int grp  = tid & 7;         // 8 col-groups of 4
  const int mcol = grp * 4;

  // Pin Whh B-frags (asm anti-remat). 2 n-frags x 8 k16 x 16B = 64 VGPR.
  floatx4 wreg[2][8];
  #pragma unroll
  for (int nf = 0; nf < 2; ++nf) {
    const __hip_bfloat16* wrow = Whh + (long)(n0 + nf*16 + col) * DH + kw + quad * 8;
    #pragma unroll
    for (int k16 = 0; k16 < 8; ++k16) {
      wreg[nf][k16] = *(const floatx4*)(wrow + k16 * 32);
      asm volatile("" : "+v"(wreg[nf][k16]));
    }
  }

  // h0 = 0 for our slice (buffer 0): write-through u64, coalesced
  st_coh64((unsigned long long*)(hbuf + (size_t)mrow * DH + n0 + mcol), 0ull);

  // XH stream t=0 (plain cached load; drained by the barrier's vmcnt(0))
  const __hip_bfloat16* xptr = XH + (size_t)mrow * T_SZ * DH + n0 + mcol;
  bf16x4 xv = *(const bf16x4*)xptr;

  arrive_and_wait(slots, 1u, bid);

  int cur = 0;
  const floatx4 Z = {0.f, 0.f, 0.f, 0.f};

  for (int t = 0; t < T_SZ; ++t) {
    // prefetch next xh inside the counted window (asm so the count is exact)
    bf16x4 xvn;
    {
      const __hip_bfloat16* xp = xptr + (size_t)(t + 1 < T_SZ ? t + 1 : t) * DH;
      LD64_COH(xvn, xp);
    }
    const __hip_bfloat16* hrow = hbuf + (size_t)cur * HELEMS + kw + quad * 8
                               + (size_t)col * DH;
    floatx4 acc[4][2];
    #pragma unroll
    for (int i = 0; i < 4; ++i) { acc[i][0] = Z; acc[i][1] = Z; }

    bf16x8 A0[8], A1[8];
    // Counted-vmcnt pipeline. Outstanding audit (xvn issued first):
    //   issue xvn+G0 (9), G1 (17) -> wait(8) retires xvn+G0
    //   issue G2 (16)             -> wait(8) retires G1
    //   issue G3 (16)             -> wait(8) retires G2
    //                                wait(0) retires G3
    ISSUE_GROUP(A0, 0);
    ISSUE_GROUP(A1, 1);
    WAIT_VM("8");
    MFMA_GROUP(A0, 0);
    ISSUE_GROUP(A0, 2);
    WAIT_VM("8");
    MFMA_GROUP(A1, 1);
    ISSUE_GROUP(A1, 3);
    WAIT_VM("8");
    MFMA_GROUP(A0, 2);
    WAIT_VM("0");
    MFMA_GROUP(A1, 3);

    // partials to LDS (C/D: m = i*16+quad*4+r, n = nf*16+col)
    #pragma unroll
    for (int i = 0; i < 4; ++i)
      #pragma unroll
      for (int nf = 0; nf < 2; ++nf)
        #pragma unroll
        for (int r = 0; r < 4; ++r)
          partial[wave][i*16 + quad*4 + r][nf*16 + col] = acc[i][nf][r];
    __syncthreads();
    // reduce 8 waves, + xh_t, relu, pack 4 n-cols, write-through u64 store
    {
      floatx4 s = Z;
      #pragma unroll
      for (int w = 0; w < NW; ++w)
        s += *(const floatx4*)(&partial[w][mrow][mcol]);
      union { bf16x4 v; __hip_bfloat16 hh[4]; unsigned long long q; } o, xu;
      xu.v = xv;
      #pragma unroll
      for (int c = 0; c < 4; ++c) {
        float v = s[c] + __bfloat162float(xu.hh[c]);
        v = v > 0.f ? v : 0.f;
        o.hh[c] = __float2bfloat16(v);
      }
      st_coh64((unsigned long long*)(hbuf + (size_t)(1 - cur) * HELEMS
                                     + (size_t)mrow * DH + n0 + mcol), o.q);
    }
    arrive_and_wait(slots, (unsigned)(t + 2), bid);
    cur ^= 1;
    xv = xvn;
  }

  // Final projection: y = h_final @ Why^T + bhy  (blocks 0..31, fp32 out).
  // Simple scheme: per 2-k16 group issue 8 coherent loads, drain vmcnt(0)
  // (safe to mix with compiler-tracked Why loads after a full drain).
  if (n0 < DOUT) {
    const __hip_bfloat16* hrow = hbuf + (size_t)cur * HELEMS + kw + quad * 8
                               + (size_t)col * DH;
    floatx4 acc[4][2];
    #pragma unroll
    for (int i = 0; i < 4; ++i) { acc[i][0] = Z; acc[i][1] = Z; }
    bf16x8 A0[8];
    #pragma unroll
    for (int g = 0; g < 4; ++g) {
      ISSUE_GROUP(A0, g);
      WAIT_VM("0");
      #pragma unroll
      for (int kk = 0; kk < 2; ++kk) {
        const int k16 = 2*g + kk;
        bf16x8 b0 = *(const bf16x8*)(Why + (long)(n0 +      col) * DH + kw + k16*32 + quad*8);
        bf16x8 b1 = *(const bf16x8*)(Why + (long)(n0 + 16 + col) * DH + kw + k16*32 + quad*8);
        #pragma unroll
        for (int i = 0; i < 4; ++i) {
          acc[i][0] = MFMA_BF16_16x16x32(A0[4*kk + i], b0, acc[i][0]);
          acc[i][1] = MFMA_BF16_16x16x32(A0[4*kk + i], b1, acc[i][1]);
        }
      }
    }
    #pragma unroll
    for (int i = 0; i < 4; ++i)
      #pragma unroll
      for (int nf = 0; nf < 2; ++nf)
        #pragma unroll
        for (int r = 0; r < 4; ++r)
          partial[wave][i*16 + quad*4 + r][nf*16 + col] = acc[i][nf][r];
    __syncthreads();
    {
      floatx4 s = Z;
      #pragma unroll
      for (int w = 0; w < NW; ++w)
        s += *(const floatx4*)(&partial[w][mrow][mcol]);
      float4 bv = *(const float4*)(&bhy[n0 + mcol]);
      float4 out;
      out.x = s[0] + bv.x; out.y = s[1] + bv.y;
      out.z = s[2] + bv.z; out.w = s[3] + bv.w;
      *(float4*)(&Y[(size_t)mrow * DOUT + n0 + mcol]) = out;
    }
  }
}

// ---------------------------------------------------------------------------
extern "C" void kernel_launch(void* const* d_in, const int* in_sizes, int n_in,
                              void* d_out, int out_size, void* d_ws, size_t ws_size,
                              hipStream_t stream) {
  const float* x   = (const float*)d_in[0];
  const float* Wxh = (const float*)d_in[1];
  const float* bxh = (const float*)d_in[2];
  const float* Whh = (const float*)d_in[3];
  const float* Why = (const float*)d_in[4];
  const float* bhy = (const float*)d_in[5];
  float* y = (float*)d_out;

  char* ws = (char*)d_ws;
  const size_t XH_BYTES  = (size_t)B_SZ * T_SZ * DH * 2;   // 128 MiB
  const size_t WHH_BYTES = (size_t)DH * DH * 2;            // 8 MiB
  const size_t WHY_BYTES = (size_t)DOUT * DH * 2;          // 4 MiB
  const size_t H_BYTES   = (size_t)2 * HELEMS * 2;         // 512 KiB
  const size_t BAR_BYTES = 64 * 256;                       // 64 slots
  __hip_bfloat16* XH     = (__hip_bfloat16*)ws;
  __hip_bfloat16* Whh_bf = (__hip_bfloat16*)(ws + XH_BYTES);
  __hip_bfloat16* Why_bf = (__hip_bfloat16*)(ws + XH_BYTES + WHH_BYTES);
  __hip_bfloat16* hbuf   = (__hip_bfloat16*)(ws + XH_BYTES + WHH_BYTES + WHY_BYTES);
  unsigned* slots        = (unsigned*)(ws + XH_BYTES + WHH_BYTES + WHY_BYTES + H_BYTES);

  hipMemsetAsync(slots, 0, BAR_BYTES, stream);
  f32_to_bf16<<<dim3((DH*DH)/(256*8)),   dim3(256), 0, stream>>>(Whh, Whh_bf, (long)DH*DH);
  f32_to_bf16<<<dim3((DOUT*DH)/(256*8)), dim3(256), 0, stream>>>(Why, Why_bf, (long)DOUT*DH);
  xh_gemm<<<dim3((32768/128) * (DH/128)), dim3(256), 0, stream>>>(x, Wxh, bxh, XH);
  elman_persistent<<<dim3(NBLK), dim3(NTHR), 0, stream>>>(
      XH, Whh_bf, Why_bf, bhy, hbuf, y, slots);
}